// Round 1
// 246.685 us; speedup vs baseline: 1.0314x; 1.0314x over previous
//
#include <hip/hip_runtime.h>

// VectorQuantizationLayer1D: N=262144 pts, D=64, K=1024 codewords.
// out (f32): [0,N) idx-as-float | [N,2N) dist | [2N,..) gathered codewords.
//
// Round 6: kill the K-loop VALU tail.
// (a) prep stores hi/lo bf16 of (-2*c); accumulator is initialized to c2, so
//     acc = c2 - 2 x.c directly after the MFMA chain (no per-element fmaf).
// (b) candidate tracking is a single packed float per slot: low 5 mantissa
//     bits carry t=ch*4+ct (codeword idx = t*32 + l31, l31 is lane-constant).
//     Update = v_and_or_b32 + v_min_f32 (2 VALU/distance, was fmaf+cmp+2сndmask),
//     perturbation <= 31 ulp (~1e-3), covered by the exact fp32 top-2 rescue.
//     Frees 32 VGPRs (bs+bi 64 regs -> bu 32 regs).
// ws layout: 8 chunks x 36864 B (hi 128x72 shorts | lo 128x72 shorts), then
// c2[1024] floats at byte 294912. Needs ws_size >= 299008.

#define N_PTS 262144
#define K_CW  1024
#define DIM   64
#define CHUNK_B 36864           // bytes per chunk image (hi+lo, stride 72 shorts)
#define C2_OFF  (8 * CHUNK_B)   // byte offset of c2[] in ws

typedef __attribute__((ext_vector_type(8)))  short short8;
typedef __attribute__((ext_vector_type(16))) float floatx16;

__device__ __forceinline__ unsigned short f2bf(float f) {
    unsigned u = __float_as_uint(f);
    return (unsigned short)((u + 0x7FFFu + ((u >> 16) & 1u)) >> 16);
}
__device__ __forceinline__ float bf2f(unsigned short h) {
    return __uint_as_float(((unsigned)h) << 16);
}
__device__ __forceinline__ float dot4(float4 a, float4 b) {
    return a.x*b.x + a.y*b.y + a.z*b.z + a.w*b.w;
}
__device__ __forceinline__ void async_cp16(const void* g, void* l) {
    __builtin_amdgcn_global_load_lds(
        (const __attribute__((address_space(1))) unsigned int*)g,
        (__attribute__((address_space(3))) unsigned int*)l, 16, 0, 0);
}

// ---- prep: split (-2*codebook) into bf16 hi/lo LDS-image + exact ||c||^2 ----
__global__ void vq_prep(const float* __restrict__ cw, unsigned char* __restrict__ ws) {
    const int k = blockIdx.x * 256 + threadIdx.x;   // codeword 0..1023
    const int ch = k >> 7, r = k & 127;
    unsigned short* chunk = (unsigned short*)(ws + (size_t)ch * CHUNK_B);
    unsigned short* hi = chunk + r * 72;
    unsigned short* lo = hi + 9216;
    const float4* cr = (const float4*)cw + (size_t)k * 16;
    float c2 = 0.f;
    #pragma unroll
    for (int j = 0; j < 16; ++j) {
        float4 v = cr[j];
        c2 += dot4(v, v);
        float4 m = make_float4(-2.f*v.x, -2.f*v.y, -2.f*v.z, -2.f*v.w);
        unsigned short h0 = f2bf(m.x), h1 = f2bf(m.y), h2 = f2bf(m.z), h3 = f2bf(m.w);
        unsigned short l0 = f2bf(m.x - bf2f(h0)), l1 = f2bf(m.y - bf2f(h1)),
                       l2 = f2bf(m.z - bf2f(h2)), l3 = f2bf(m.w - bf2f(h3));
        uint2 hv, lv;
        hv.x = (unsigned)h0 | ((unsigned)h1 << 16);
        hv.y = (unsigned)h2 | ((unsigned)h3 << 16);
        lv.x = (unsigned)l0 | ((unsigned)l1 << 16);
        lv.y = (unsigned)l2 | ((unsigned)l3 << 16);
        *(uint2*)(hi + j * 4) = hv;
        *(uint2*)(lo + j * 4) = lv;
    }
    ((float*)(ws + C2_OFF))[k] = c2;
}

__launch_bounds__(256, 2)
__global__ void vq_kernel(const float* __restrict__ x,
                          const float* __restrict__ cw,
                          const unsigned char* __restrict__ ws,
                          float* __restrict__ out) {
    __shared__ __align__(16) unsigned char sB[2 * CHUNK_B];   // 72 KB double buffer
    // epilogue scratch aliases buf0 (dead after the K loop)
    int*   sci  = (int*)sB;              // [0, 2048)
    float* sdd  = (float*)(sB + 2048);   // [2048, 4096)
    int*   sidx = (int*)(sB + 4096);     // [4096, 5120)

    const int tid  = threadIdx.x;
    const int w    = tid >> 6;
    const int lane = tid & 63;
    const int q    = lane >> 5;
    const int l31  = lane & 31;
    const int base = blockIdx.x * 256;
    const float4* __restrict__ x4  = (const float4*)x;
    const float4* __restrict__ c4p = (const float4*)cw;
    const float*  __restrict__ c2g = (const float*)(ws + C2_OFF);

    // ---- A fragments from global: wave w owns rows [w*64, w*64+64) ----
    short8 ah[2][4], al[2][4];
    #pragma unroll
    for (int rt = 0; rt < 2; ++rt) {
        const int row = w * 64 + rt * 32 + l31;
        const float4* xr = x4 + (size_t)(base + row) * 16;
        #pragma unroll
        for (int ks = 0; ks < 4; ++ks) {
            float4 va = xr[ks * 4 + q * 2];
            float4 vb = xr[ks * 4 + q * 2 + 1];
            float f[8] = {va.x, va.y, va.z, va.w, vb.x, vb.y, vb.z, vb.w};
            short8 h, l;
            #pragma unroll
            for (int j = 0; j < 8; ++j) {
                unsigned short hb = f2bf(f[j]);
                h[j] = (short)hb;
                l[j] = (short)f2bf(f[j] - bf2f(hb));
            }
            ah[rt][ks] = h; al[rt][ks] = l;
        }
    }

    // packed candidates: float bits = (c2 - 2x.c) with low 5 mantissa bits = t
    float bu[32];
    #pragma unroll
    for (int s = 0; s < 32; ++s) bu[s] = 3.4e38f;

    // pre-issue chunk 0 DMA into buf0 (each wave copies its 9 KB quarter)
    {
        const unsigned char* g = ws + w * 9216 + lane * 16;
        unsigned char* l = sB + w * 9216;
        #pragma unroll
        for (int i = 0; i < 9; ++i) async_cp16(g + i * 1024, l + i * 1024);
    }

    // ---- K loop: 8 chunks of 128 codewords, single barrier per chunk ----
    for (int ch = 0; ch < 8; ++ch) {
        __syncthreads();   // own DMA drained (vmcnt0) + all waves' DMA for ch landed

        if (ch < 7) {      // prefetch ch+1 into other buffer; hidden under compute
            const unsigned char* g = ws + (size_t)(ch + 1) * CHUNK_B + w * 9216 + lane * 16;
            unsigned char* l = sB + ((ch + 1) & 1) * CHUNK_B + w * 9216;
            #pragma unroll
            for (int i = 0; i < 9; ++i) async_cp16(g + i * 1024, l + i * 1024);
        }

        float c2v[4];
        #pragma unroll
        for (int ct = 0; ct < 4; ++ct) c2v[ct] = c2g[ch * 128 + ct * 32 + l31];

        const unsigned short* bufS = (const unsigned short*)(sB + (ch & 1) * CHUNK_B);

        #pragma unroll
        for (int ct = 0; ct < 4; ++ct) {
            const int nrow = ct * 32 + l31;
            short8 bh[4], bl[4];
            #pragma unroll
            for (int ks = 0; ks < 4; ++ks) {
                bh[ks] = *(const short8*)&bufS[nrow * 72 + ks * 16 + q * 8];
                bl[ks] = *(const short8*)&bufS[9216 + nrow * 72 + ks * 16 + q * 8];
            }
            // acc starts at c2 (B is pre-scaled by -2): acc = c2 - 2 x.c
            floatx16 a0, a1;
            #pragma unroll
            for (int r = 0; r < 16; ++r) { a0[r] = c2v[ct]; a1[r] = c2v[ct]; }
            #pragma unroll
            for (int ks = 0; ks < 4; ++ks) {   // hh, lh, hl; 2 indep chains
                a0 = __builtin_amdgcn_mfma_f32_32x32x16_bf16(ah[0][ks], bh[ks], a0, 0, 0, 0);
                a1 = __builtin_amdgcn_mfma_f32_32x32x16_bf16(ah[1][ks], bh[ks], a1, 0, 0, 0);
                a0 = __builtin_amdgcn_mfma_f32_32x32x16_bf16(al[0][ks], bh[ks], a0, 0, 0, 0);
                a1 = __builtin_amdgcn_mfma_f32_32x32x16_bf16(al[1][ks], bh[ks], a1, 0, 0, 0);
                a0 = __builtin_amdgcn_mfma_f32_32x32x16_bf16(ah[0][ks], bl[ks], a0, 0, 0, 0);
                a1 = __builtin_amdgcn_mfma_f32_32x32x16_bf16(ah[1][ks], bl[ks], a1, 0, 0, 0);
            }
            const unsigned tch = (unsigned)(ch * 4 + ct);   // 5-bit slot tag
            #pragma unroll
            for (int r = 0; r < 16; ++r) {
                unsigned u0 = (__float_as_uint(a0[r]) & 0xFFFFFFE0u) | tch;
                bu[r] = fminf(bu[r], __uint_as_float(u0));
                unsigned u1 = (__float_as_uint(a1[r]) & 0xFFFFFFE0u) | tch;
                bu[16 + r] = fminf(bu[16 + r], __uint_as_float(u1));
            }
        }
    }
    __syncthreads();   // all B reads done before buf0 is reused as scratch

    // ---- per-slot shfl butterfly: top-2 across the 32 column-classes ----
    #pragma unroll
    for (int s = 0; s < 32; ++s) {
        float b0 = bu[s];
        int i0 = (int)(((__float_as_uint(b0) & 31u) << 5) | (unsigned)l31);
        float b1 = 3.4e38f; int i1 = 0x7fffffff;
        #pragma unroll
        for (int m = 1; m < 32; m <<= 1) {
            float ob0 = __shfl_xor(b0, m); int oi0 = __shfl_xor(i0, m);
            float ob1 = __shfl_xor(b1, m); int oi1 = __shfl_xor(i1, m);
            bool t = (ob0 < b0) || (ob0 == b0 && oi0 < i0);
            float hs = t ? b0 : ob0; int hi_ = t ? i0 : oi0;   // loser of firsts
            b0 = t ? ob0 : b0;       i0 = t ? oi0 : i0;
            bool u = (ob1 < b1) || (ob1 == b1 && oi1 < i1);
            float ms = u ? ob1 : b1; int mi = u ? oi1 : i1;    // winner of seconds
            bool z = (hs < ms) || (hs == ms && hi_ < mi);
            b1 = z ? hs : ms; i1 = z ? hi_ : mi;
        }
        if (l31 == s) {
            const int rt = s >> 4, r = s & 15;
            const int row = w * 64 + rt * 32 + (r & 3) + 8 * (r >> 2) + 4 * q;
            sci[row * 2]     = i0;
            sci[row * 2 + 1] = i1;
        }
    }
    __syncthreads();

    // ---- exact fp32 rescore (diff^2), 2 threads per point ----
    #pragma unroll
    for (int it = 0; it < 2; ++it) {
        const int pid = it * 128 + (tid >> 1);
        const int h   = tid & 1;
        const int ia = sci[pid * 2], ib = sci[pid * 2 + 1];
        const float4* xr = x4 + (size_t)(base + pid) * 16 + h * 8;
        const float4* ca = c4p + (size_t)ia * 16 + h * 8;
        const float4* cb = c4p + (size_t)ib * 16 + h * 8;
        float da = 0.f, db = 0.f;
        #pragma unroll
        for (int j = 0; j < 8; ++j) {
            float4 xv = xr[j], av = ca[j], bv = cb[j];
            float4 d1 = make_float4(xv.x-av.x, xv.y-av.y, xv.z-av.z, xv.w-av.w);
            float4 d2 = make_float4(xv.x-bv.x, xv.y-bv.y, xv.z-bv.z, xv.w-bv.w);
            da += dot4(d1, d1);
            db += dot4(d2, d2);
        }
        da += __shfl_xor(da, 1);
        db += __shfl_xor(db, 1);
        if (h == 0) { sdd[pid * 2] = da; sdd[pid * 2 + 1] = db; }
    }
    __syncthreads();

    {   // final pick + scalar outputs (tie -> lower index, np argmin)
        const float da = sdd[tid * 2], db = sdd[tid * 2 + 1];
        const int   ia = sci[tid * 2], ib = sci[tid * 2 + 1];
        bool ta = (da < db) || (da == db && ia < ib);
        const int   bidx = ta ? ia : ib;
        const float bd   = ta ? da : db;
        out[base + tid]         = (float)bidx;
        out[N_PTS + base + tid] = sqrtf(fmaxf(bd, 0.f));
        sidx[tid] = bidx;
    }
    __syncthreads();

    // ---- gather quantized_data (coalesced float4 writes; cw is L2-hot) ----
    {
        float4* od = (float4*)(out + 2 * (size_t)N_PTS) + (size_t)base * 16;
        #pragma unroll
        for (int i = 0; i < 16; ++i) {
            const int g = i * 256 + tid;
            od[g] = c4p[(size_t)sidx[g >> 4] * 16 + (g & 15)];
        }
    }
}

extern "C" void kernel_launch(void* const* d_in, const int* in_sizes, int n_in,
                              void* d_out, int out_size, void* d_ws, size_t ws_size,
                              hipStream_t stream) {
    const float* x  = (const float*)d_in[0];
    const float* cw = (const float*)d_in[1];
    float* out = (float*)d_out;
    unsigned char* ws = (unsigned char*)d_ws;
    vq_prep<<<4, 256, 0, stream>>>(cw, ws);
    vq_kernel<<<N_PTS / 256, 256, 0, stream>>>(x, cw, ws, out);
}